// Round 1
// baseline (436.394 us; speedup 1.0000x reference)
//
#include <hip/hip_runtime.h>
#include <hip/hip_bf16.h>
#include <math.h>

#define N_NODES 100000
#define N_EDGES 1600000
#define NFEAT 256
#define NHID1 128
#define NCLASS 64
#define NUM_GRAPHS 64

// bucket geometry: bucket = col >> 8 (256 nodes per bucket)
#define NBUCK 391                    // ceil(100000/256)
#define EPB 8192                     // edges per block in binning passes
#define NBLK_A 196                   // ceil(1600000/8192)

typedef __attribute__((ext_vector_type(8))) short bf16x8;
typedef __attribute__((ext_vector_type(4))) float f32x4;
typedef __attribute__((ext_vector_type(4))) unsigned u32x4;

// ---------------- bf16 helpers (bit-level, RNE) ----------------

__device__ __forceinline__ unsigned short f2bf(float f) {
    unsigned u = __float_as_uint(f);
    u += 0x7fffu + ((u >> 16) & 1u);   // round to nearest even
    return (unsigned short)(u >> 16);
}
__device__ __forceinline__ unsigned packbf2(float lo, float hi) {
    return (unsigned)f2bf(lo) | ((unsigned)f2bf(hi) << 16);
}
__device__ __forceinline__ float bflo(unsigned p) { return __uint_as_float(p << 16); }
__device__ __forceinline__ float bfhi(unsigned p) { return __uint_as_float(p & 0xffff0000u); }

// ---------------- pass A1: bucket histogram (block-aggregated atomics) ----------------

__global__ __launch_bounds__(256) void hist_kernel(const int* __restrict__ cols,
                                                   int* __restrict__ ghist, int nE) {
    __shared__ int h[NBUCK];
    const int tid = threadIdx.x;
    for (int i = tid; i < NBUCK; i += 256) h[i] = 0;
    __syncthreads();
    long base = (long)blockIdx.x * EPB;
    for (int j = tid; j < EPB; j += 256) {
        long idx = base + j;
        if (idx < nE) atomicAdd(&h[cols[idx] >> 8], 1);
    }
    __syncthreads();
    for (int i = tid; i < NBUCK; i += 256) {
        int v = h[i];
        if (v) atomicAdd(&ghist[i], v);
    }
}

// ---------------- bucket scan: 391 entries -> gbase, gcursor ----------------

__global__ __launch_bounds__(512) void bucket_scan_kernel(const int* __restrict__ ghist,
                                                          int* __restrict__ gbase,
                                                          int* __restrict__ gcursor) {
    __shared__ int sh[512];
    int t = threadIdx.x;
    int v = (t < NBUCK) ? ghist[t] : 0;
    sh[t] = v;
    __syncthreads();
    for (int off = 1; off < 512; off <<= 1) {
        int add = (t >= off) ? sh[t - off] : 0;
        __syncthreads();
        sh[t] += add;
        __syncthreads();
    }
    if (t < NBUCK) {
        int excl = sh[t] - v;
        gbase[t] = excl;
        gcursor[t] = excl;
    }
}

// ---------------- pass A2: scatter edges into bucket-grouped csc_tmp ----------------
// record: .x = r | ((col&255)<<17), .y = w bits

__global__ __launch_bounds__(256) void scatter_bucket_kernel(const int* __restrict__ rows,
                                                             const int* __restrict__ cols,
                                                             const float* __restrict__ w,
                                                             int* __restrict__ gcursor,
                                                             int2* __restrict__ csc_tmp, int nE) {
    __shared__ int h[NBUCK];
    __shared__ int bb[NBUCK];
    __shared__ unsigned short rk[EPB];
    const int tid = threadIdx.x;
    for (int i = tid; i < NBUCK; i += 256) h[i] = 0;
    __syncthreads();
    long base = (long)blockIdx.x * EPB;
    for (int j = tid; j < EPB; j += 256) {
        long idx = base + j;
        if (idx < nE) rk[j] = (unsigned short)atomicAdd(&h[cols[idx] >> 8], 1);
    }
    __syncthreads();
    for (int i = tid; i < NBUCK; i += 256) {
        int v = h[i];
        if (v) bb[i] = atomicAdd(&gcursor[i], v);
    }
    __syncthreads();
    for (int j = tid; j < EPB; j += 256) {
        long idx = base + j;
        if (idx < nE) {
            int c = cols[idx];
            int b = c >> 8;
            int pos = bb[b] + (int)rk[j];
            csc_tmp[pos] = make_int2((rows[idx] & 0x1FFFF) | ((c & 255) << 17),
                                     __float_as_int(w[idx]));
        }
    }
}

// ---------------- pass B: per-bucket node-level CSC + deg/dinv + starts/cnt ----------------

__global__ __launch_bounds__(256) void build_csc_kernel(const int2* __restrict__ csc_tmp,
                                                        const int* __restrict__ gbase,
                                                        const int* __restrict__ ghist,
                                                        int2* __restrict__ edges,
                                                        int* __restrict__ starts,
                                                        int* __restrict__ cnt,
                                                        float* __restrict__ dinv, int n) {
    __shared__ int ncnt[256];
    __shared__ float nws[256];
    __shared__ int sh[256];
    __shared__ int ncur[256];
    const int tid = threadIdx.x;
    const int b = blockIdx.x;
    const int base = gbase[b];
    const int cntb = ghist[b];

    ncnt[tid] = 0;
    nws[tid] = 0.f;
    __syncthreads();

    // sweep 1: per-node count + weight sum
    for (int i = tid; i < cntb; i += 256) {
        int2 rec = csc_tmp[base + i];
        int local = ((unsigned)rec.x) >> 17;
        atomicAdd(&ncnt[local], 1);
        atomicAdd(&nws[local], __int_as_float(rec.y));
    }
    __syncthreads();

    // exclusive scan over 256 node counts
    int v = ncnt[tid];
    sh[tid] = v;
    __syncthreads();
    for (int off = 1; off < 256; off <<= 1) {
        int add = (tid >= off) ? sh[tid - off] : 0;
        __syncthreads();
        sh[tid] += add;
        __syncthreads();
    }
    int excl = sh[tid] - v;
    ncur[tid] = excl;

    int node = (b << 8) + tid;
    if (node < n) {
        cnt[node] = v;
        starts[node] = base + excl;
        dinv[node] = rsqrtf(1.0f + nws[tid]);
    }
    __syncthreads();

    // sweep 2: place edges at exact node positions
    for (int i = tid; i < cntb; i += 256) {
        int2 rec = csc_tmp[base + i];
        int local = ((unsigned)rec.x) >> 17;
        int r = rec.x & 0x1FFFF;
        int pos = base + atomicAdd(&ncur[local], 1);
        edges[pos] = make_int2(r, rec.y);
    }
}

// ---------------- weight transpose + bf16 pack: W[K][Nn] f32 -> WT[Nn][K/2] dwords ----------------

__global__ void transpose_bf_kernel(const float* __restrict__ W, unsigned* __restrict__ WT,
                                    int K, int Nn) {
    int idx = blockIdx.x * blockDim.x + threadIdx.x;
    int total = Nn * (K / 2);
    if (idx < total) {
        int n = idx / (K / 2);
        int kp = idx - n * (K / 2);
        WT[idx] = packbf2(W[(2 * kp) * Nn + n], W[(2 * kp + 1) * Nn + n]);
    }
}

// ---------------- MFMA bf16 GEMM: C[M,NT] = A[M,KK] @ BT^T, epilogue *rowscale -> bf16 ----------------

template <int NT, int KK, bool ABF16>
__global__ __launch_bounds__(256) void gemm_mfma(const void* __restrict__ Av,
                                                 const unsigned* __restrict__ BT,
                                                 const float* __restrict__ rowscale,
                                                 unsigned short* __restrict__ C,
                                                 int M) {
    constexpr int CT = NT / 16;
    constexpr int KD = KK / 2;          // dwords per bf16 row
    __shared__ unsigned Al[4][128][4];
    __shared__ unsigned Bl[4][NT][4];
    const int tid = threadIdx.x;
    const int wave = tid >> 6;
    const int lane = tid & 63;
    const int quad = lane >> 4;
    const int l16 = lane & 15;
    const int row0 = blockIdx.x * 128;

    f32x4 acc[2][CT] = {};

    for (int k0 = 0; k0 < KK; k0 += 32) {
        // ---- stage A ----
        if (ABF16) {
            const unsigned* Ab = (const unsigned*)Av;
            #pragma unroll
            for (int i = 0; i < 2; i++) {
                int idx = tid + i * 256;
                int ar = idx >> 2, aq = idx & 3;
                uint4 v = make_uint4(0, 0, 0, 0);
                if (row0 + ar < M)
                    v = *(const uint4*)(Ab + (long)(row0 + ar) * KD + k0 / 2 + aq * 4);
                *(uint4*)&Al[aq][ar][0] = v;
            }
        } else {
            const float* Af = (const float*)Av;
            int ar = tid >> 1, ah = tid & 1;
            float4 v0 = make_float4(0, 0, 0, 0), v1 = v0, v2 = v0, v3 = v0;
            if (row0 + ar < M) {
                const float* p = Af + (long)(row0 + ar) * KK + k0 + ah * 16;
                v0 = *(const float4*)p;
                v1 = *(const float4*)(p + 4);
                v2 = *(const float4*)(p + 8);
                v3 = *(const float4*)(p + 12);
            }
            uint4 d0 = make_uint4(packbf2(v0.x, v0.y), packbf2(v0.z, v0.w),
                                  packbf2(v1.x, v1.y), packbf2(v1.z, v1.w));
            uint4 d1 = make_uint4(packbf2(v2.x, v2.y), packbf2(v2.z, v2.w),
                                  packbf2(v3.x, v3.y), packbf2(v3.z, v3.w));
            *(uint4*)&Al[ah * 2 + 0][ar][0] = d0;
            *(uint4*)&Al[ah * 2 + 1][ar][0] = d1;
        }
        // ---- stage B ----
        #pragma unroll
        for (int i = 0; i < NT / 64; i++) {
            int idx = tid + i * 256;
            int br = idx >> 2, bq = idx & 3;
            *(uint4*)&Bl[bq][br][0] = *(const uint4*)(BT + (long)br * KD + k0 / 2 + bq * 4);
        }
        __syncthreads();

        bf16x8 af[2];
        #pragma unroll
        for (int rt = 0; rt < 2; rt++)
            af[rt] = *(const bf16x8*)&Al[quad][wave * 32 + rt * 16 + l16][0];
        #pragma unroll
        for (int ct = 0; ct < CT; ct++) {
            bf16x8 bfr = *(const bf16x8*)&Bl[quad][ct * 16 + l16][0];
            acc[0][ct] = __builtin_amdgcn_mfma_f32_16x16x32_bf16(af[0], bfr, acc[0][ct], 0, 0, 0);
            acc[1][ct] = __builtin_amdgcn_mfma_f32_16x16x32_bf16(af[1], bfr, acc[1][ct], 0, 0, 0);
        }
        __syncthreads();
    }

    // epilogue: C/D layout col=lane&15, row=quad*4+reg
    #pragma unroll
    for (int rt = 0; rt < 2; rt++) {
        #pragma unroll
        for (int reg = 0; reg < 4; reg++) {
            int row = row0 + wave * 32 + rt * 16 + quad * 4 + reg;
            if (row < M) {
                float sc = rowscale[row];
                unsigned short* cp = C + (long)row * NT + l16;
                #pragma unroll
                for (int ct = 0; ct < CT; ct++)
                    cp[ct * 16] = f2bf(acc[rt][ct][reg] * sc);
            }
        }
    }
}

// ---------------- gather-aggregate over bf16 features ----------------
// OUTMODE: 0 = f32 out, 1 = bf16 out (nontemporal), 2 = fused global-add-pool
// Edge-record loads are nontemporal (stream, never reused within the kernel)
// so they do not evict the random-gather working set from L2.

template <int F, bool RELU, int OUTMODE>
__global__ __launch_bounds__(256) void gather_agg_bf(const unsigned* __restrict__ xsb,
                                                     const int2* __restrict__ edges,
                                                     const int* __restrict__ starts,
                                                     const int* __restrict__ cnt,
                                                     const float* __restrict__ dinv,
                                                     const float* __restrict__ bias,
                                                     const int* __restrict__ batch,
                                                     void* __restrict__ outv, int n) {
    constexpr int G = F / 8;        // lanes per node; each lane covers 8 features
    constexpr int FU = F / 2;       // uints per row
    int gt = blockIdx.x * blockDim.x + threadIdx.x;
    int node = gt / G;
    int lane = gt - node * G;

    if (OUTMODE != 2 && node >= n) return;
    bool active = (node < n);

    // LDS pool buckets (only used for OUTMODE==2)
    __shared__ float lp[4][64];
    int g0 = 0;
    if (OUTMODE == 2) {
        lp[threadIdx.x >> 6][threadIdx.x & 63] = 0.f;
        int firstnode = (blockIdx.x * blockDim.x) / G;
        if (firstnode >= n) firstnode = n - 1;
        g0 = batch[firstnode];
        __syncthreads();
    }

    float acc[8] = {};
    float d = 0.f;
    const unsigned* lbase = xsb + lane * 4;

    if (active) {
        int s = starts[node];
        int c = cnt[node];
        int e = s + c;

        int j = s;
        // unroll 4: batch edge-record loads (nontemporal), then 4 independent gathers in flight
        for (; j + 3 < e; j += 4) {
            long long q0 = __builtin_nontemporal_load((const long long*)(edges + j));
            long long q1 = __builtin_nontemporal_load((const long long*)(edges + j + 1));
            long long q2 = __builtin_nontemporal_load((const long long*)(edges + j + 2));
            long long q3 = __builtin_nontemporal_load((const long long*)(edges + j + 3));
            int r0 = (int)q0, r1 = (int)q1, r2 = (int)q2, r3 = (int)q3;
            float w0 = __int_as_float((int)(q0 >> 32));
            float w1 = __int_as_float((int)(q1 >> 32));
            float w2 = __int_as_float((int)(q2 >> 32));
            float w3 = __int_as_float((int)(q3 >> 32));
            uint4 p0 = *(const uint4*)(lbase + (long)r0 * FU);
            uint4 p1 = *(const uint4*)(lbase + (long)r1 * FU);
            uint4 p2 = *(const uint4*)(lbase + (long)r2 * FU);
            uint4 p3 = *(const uint4*)(lbase + (long)r3 * FU);
            acc[0] += bflo(p0.x) * w0; acc[1] += bfhi(p0.x) * w0;
            acc[2] += bflo(p0.y) * w0; acc[3] += bfhi(p0.y) * w0;
            acc[4] += bflo(p0.z) * w0; acc[5] += bfhi(p0.z) * w0;
            acc[6] += bflo(p0.w) * w0; acc[7] += bfhi(p0.w) * w0;
            acc[0] += bflo(p1.x) * w1; acc[1] += bfhi(p1.x) * w1;
            acc[2] += bflo(p1.y) * w1; acc[3] += bfhi(p1.y) * w1;
            acc[4] += bflo(p1.z) * w1; acc[5] += bfhi(p1.z) * w1;
            acc[6] += bflo(p1.w) * w1; acc[7] += bfhi(p1.w) * w1;
            acc[0] += bflo(p2.x) * w2; acc[1] += bfhi(p2.x) * w2;
            acc[2] += bflo(p2.y) * w2; acc[3] += bfhi(p2.y) * w2;
            acc[4] += bflo(p2.z) * w2; acc[5] += bfhi(p2.z) * w2;
            acc[6] += bflo(p2.w) * w2; acc[7] += bfhi(p2.w) * w2;
            acc[0] += bflo(p3.x) * w3; acc[1] += bfhi(p3.x) * w3;
            acc[2] += bflo(p3.y) * w3; acc[3] += bfhi(p3.y) * w3;
            acc[4] += bflo(p3.z) * w3; acc[5] += bfhi(p3.z) * w3;
            acc[6] += bflo(p3.w) * w3; acc[7] += bfhi(p3.w) * w3;
        }
        for (; j < e; j++) {
            long long q = __builtin_nontemporal_load((const long long*)(edges + j));
            int r = (int)q;
            float wv = __int_as_float((int)(q >> 32));
            uint4 p = *(const uint4*)(lbase + (long)r * FU);
            acc[0] += bflo(p.x) * wv; acc[1] += bfhi(p.x) * wv;
            acc[2] += bflo(p.y) * wv; acc[3] += bfhi(p.y) * wv;
            acc[4] += bflo(p.z) * wv; acc[5] += bfhi(p.z) * wv;
            acc[6] += bflo(p.w) * wv; acc[7] += bfhi(p.w) * wv;
        }
        d = dinv[node];
    }

    float r[8] = {};
    if (active) {
        uint4 sp = *(const uint4*)(lbase + (long)node * FU);
        float sv[8] = { bflo(sp.x), bfhi(sp.x), bflo(sp.y), bfhi(sp.y),
                        bflo(sp.z), bfhi(sp.z), bflo(sp.w), bfhi(sp.w) };
        float4 bb0 = ((const float4*)bias)[lane * 2];
        float4 bb1 = ((const float4*)bias)[lane * 2 + 1];
        float bbv[8] = { bb0.x, bb0.y, bb0.z, bb0.w, bb1.x, bb1.y, bb1.z, bb1.w };
        #pragma unroll
        for (int i = 0; i < 8; i++) {
            float v = d * (acc[i] + sv[i]) + bbv[i];
            r[i] = RELU ? fmaxf(v, 0.f) : v;
        }
    }

    if (OUTMODE == 1) {
        if (active) {
            unsigned* ob = (unsigned*)outv;
            u32x4 pk = { packbf2(r[0], r[1]), packbf2(r[2], r[3]),
                         packbf2(r[4], r[5]), packbf2(r[6], r[7]) };
            __builtin_nontemporal_store(pk, (u32x4*)(ob + (long)node * FU + lane * 4));
        }
    } else if (OUTMODE == 0) {
        if (active) {
            float* o = (float*)outv + (long)node * F + lane * 8;
            *(float4*)o       = make_float4(r[0], r[1], r[2], r[3]);
            *(float4*)(o + 4) = make_float4(r[4], r[5], r[6], r[7]);
        }
    } else {
        // fused global_add_pool: LDS partial sums by (graph - g0), then few atomics
        float* pooled = (float*)outv;
        if (active) {
            int g = batch[node];
            int rel = g - g0;
            if (rel >= 0 && rel < 4) {
                #pragma unroll
                for (int i = 0; i < 8; i++)
                    atomicAdd(&lp[rel][lane * 8 + i], r[i]);
            } else {
                #pragma unroll
                for (int i = 0; i < 8; i++)
                    atomicAdd(&pooled[g * 64 + lane * 8 + i], r[i]);
            }
        }
        __syncthreads();
        int idx = threadIdx.x;           // 256 threads cover 4x64 slots exactly
        int rel = idx >> 6, feat = idx & 63;
        float v = lp[rel][feat];
        int g = g0 + rel;
        if (v != 0.f && g < NUM_GRAPHS)
            atomicAdd(&pooled[g * 64 + feat], v);
    }
}

// ---------------- head: 256 threads, all-LDS MLP + log_softmax + argmax ----------------

__global__ __launch_bounds__(256) void head_kernel(const float* __restrict__ pooled,
                                                   const float* __restrict__ l1w,
                                                   const float* __restrict__ l1b,
                                                   const float* __restrict__ l2w,
                                                   const float* __restrict__ l2b,
                                                   float* __restrict__ out) {
    __shared__ float P[64][68];
    __shared__ float W[64][68];
    __shared__ float red0[64][4];
    __shared__ float red1[64][4];
    const int tid = threadIdx.x;

    for (int i = tid; i < 1024; i += 256) {
        int r = i >> 4;
        int cq = (i & 15) * 4;
        *(float4*)&P[r][cq] = *(const float4*)&pooled[r * 64 + cq];
        *(float4*)&W[r][cq] = *(const float4*)&l1w[r * 64 + cq];
    }
    __syncthreads();

    const int g = tid >> 2;
    const int q = tid & 3;
    const int j0 = q * 16;

    float hacc[16];
    #pragma unroll
    for (int jj = 0; jj < 16; jj++) hacc[jj] = l1b[j0 + jj];

    for (int c = 0; c < 64; c++) {
        float pv = P[g][c];
        #pragma unroll
        for (int jj = 0; jj < 16; jj += 4) {
            float4 wv = *(const float4*)&W[c][j0 + jj];
            hacc[jj + 0] += pv * wv.x;
            hacc[jj + 1] += pv * wv.y;
            hacc[jj + 2] += pv * wv.z;
            hacc[jj + 3] += pv * wv.w;
        }
    }

    float o0 = 0.f, o1 = 0.f;
    #pragma unroll
    for (int jj = 0; jj < 16; jj++) {
        float h = fmaxf(hacc[jj], 0.f);
        o0 += h * l2w[(j0 + jj) * 2];
        o1 += h * l2w[(j0 + jj) * 2 + 1];
    }
    red0[g][q] = o0;
    red1[g][q] = o1;
    __syncthreads();

    if (q == 0) {
        float a0 = red0[g][0] + red0[g][1] + red0[g][2] + red0[g][3] + l2b[0];
        float a1 = red1[g][0] + red1[g][1] + red1[g][2] + red1[g][3] + l2b[1];
        float m = fmaxf(a0, a1);
        float lse = m + logf(expf(a0 - m) + expf(a1 - m));
        out[g * 2 + 0] = a0 - lse;
        out[g * 2 + 1] = a1 - lse;
        out[128 + g] = (a1 > a0) ? 1.f : 0.f;
        out[192 + g * 2 + 0] = a0;
        out[192 + g * 2 + 1] = a1;
    }
}

// ---------------- launch ----------------

extern "C" void kernel_launch(void* const* d_in, const int* in_sizes, int n_in,
                              void* d_out, int out_size, void* d_ws, size_t ws_size,
                              hipStream_t stream) {
    const float* x   = (const float*)d_in[0];           // [N, 256]
    const int* eidx  = (const int*)d_in[1];             // [2, E] flat
    const float* ew  = (const float*)d_in[2];           // [E]
    const int* batch = (const int*)d_in[3];             // [N]
    const float* W1  = (const float*)d_in[4];           // [256,128]
    const float* b1  = (const float*)d_in[5];
    const float* W2  = (const float*)d_in[6];           // [128,64]
    const float* b2  = (const float*)d_in[7];
    const float* l1w = (const float*)d_in[8];           // [64,64]
    const float* l1b = (const float*)d_in[9];
    const float* l2w = (const float*)d_in[10];          // [64,2]
    const float* l2b = (const float*)d_in[11];
    float* out = (float*)d_out;

    const int N = N_NODES, E = N_EDGES;
    const int* rows = eidx;
    const int* cols = eidx + E;

    // workspace layout (float offsets; 16B alignment for vector arrays)
    float* ws = (float*)d_ws;
    int*   ghist   = (int*)ws;                  // 391   -> pad to 512
    int*   gbase   = ghist + 512;               // 391   -> pad to 512
    int*   gcursor = gbase + 512;               // 391   -> pad to 512
    float* dinv    = (float*)(gcursor + 512);   // N
    int*   cnt     = (int*)(dinv + N);          // N
    int*   starts  = cnt + N;                   // N
    unsigned* w1t  = (unsigned*)(starts + N);   // 16384
    unsigned* w2t  = w1t + 16384;               // 4096
    int2*  csc_tmp = (int2*)(w2t + 4096);       // E int2 (16B-aligned)
    int2*  edges   = csc_tmp + E;               // E int2
    unsigned* xsb  = (unsigned*)(edges + E);    // N*64 dw
    unsigned* h1b  = xsb + (long)N * 64;        // N*64 dw
    float* pooled  = (float*)(h1b + (long)N * 64);  // 4096
    unsigned* hw2b = xsb;                       // reuse dead xsb: N*32 dw

    // 1. bucket histogram (block-aggregated atomics)
    hipMemsetAsync(ghist, 0, 512 * sizeof(int), stream);
    hist_kernel<<<NBLK_A, 256, 0, stream>>>(cols, ghist, E);

    // 2. bucket scan
    bucket_scan_kernel<<<1, 512, 0, stream>>>(ghist, gbase, gcursor);

    // 3. scatter into bucket-grouped tmp
    scatter_bucket_kernel<<<NBLK_A, 256, 0, stream>>>(rows, cols, ew, gcursor, csc_tmp, E);

    // 4. per-bucket node-level CSC + deg/dinv/starts/cnt
    build_csc_kernel<<<NBUCK, 256, 0, stream>>>(csc_tmp, gbase, ghist, edges, starts, cnt, dinv, N);

    // 5. weight prep
    transpose_bf_kernel<<<64, 256, 0, stream>>>(W1, w1t, NFEAT, NHID1);
    transpose_bf_kernel<<<16, 256, 0, stream>>>(W2, w2t, NHID1, NCLASS);

    // 6. GEMM1 (MFMA): xsb = bf16((x @ W1) * dinv[row])
    gemm_mfma<NHID1, NFEAT, false><<<(N + 127) / 128, 256, 0, stream>>>(
        x, w1t, dinv, (unsigned short*)xsb, N);

    // 7. gather layer 1: h1b = bf16(relu(dinv[c]*(agg + self) + b1))  [nontemporal out]
    {
        long threads = (long)N * (NHID1 / 8);
        gather_agg_bf<NHID1, true, 1><<<(threads + 255) / 256, 256, 0, stream>>>(
            xsb, edges, starts, cnt, dinv, b1, batch, h1b, N);
    }

    // 8. GEMM2 (MFMA): hw2b = bf16((h1 @ W2) * dinv[row])  (into dead xsb region)
    gemm_mfma<NCLASS, NHID1, true><<<(N + 127) / 128, 256, 0, stream>>>(
        h1b, w2t, dinv, (unsigned short*)hw2b, N);

    // 9. gather layer 2 + fused global_add_pool (no h2 materialization)
    hipMemsetAsync(pooled, 0, NUM_GRAPHS * NCLASS * sizeof(float), stream);
    {
        long threads = (long)N * (NCLASS / 8);
        gather_agg_bf<NCLASS, true, 2><<<(threads + 255) / 256, 256, 0, stream>>>(
            hw2b, edges, starts, cnt, dinv, b2, batch, pooled, N);
    }

    // 10. head
    head_kernel<<<1, 256, 0, stream>>>(pooled, l1w, l1b, l2w, l2b, out);
}

// Round 2
// 418.377 us; speedup vs baseline: 1.0431x; 1.0431x over previous
//
#include <hip/hip_runtime.h>
#include <hip/hip_bf16.h>
#include <math.h>

#define N_NODES 100000
#define N_EDGES 1600000
#define NFEAT 256
#define NHID1 128
#define NCLASS 64
#define NUM_GRAPHS 64

// bucket geometry: bucket = col >> 8 (256 nodes per bucket)
#define NBUCK 391                    // ceil(100000/256)
#define EPB 8192                     // edges per block in binning passes
#define NBLK_A 196                   // ceil(1600000/8192)

typedef __attribute__((ext_vector_type(8))) short bf16x8;
typedef __attribute__((ext_vector_type(4))) float f32x4;

// ---------------- bf16 helpers (bit-level, RNE) ----------------

__device__ __forceinline__ unsigned short f2bf(float f) {
    unsigned u = __float_as_uint(f);
    u += 0x7fffu + ((u >> 16) & 1u);   // round to nearest even
    return (unsigned short)(u >> 16);
}
__device__ __forceinline__ unsigned packbf2(float lo, float hi) {
    return (unsigned)f2bf(lo) | ((unsigned)f2bf(hi) << 16);
}
__device__ __forceinline__ float bflo(unsigned p) { return __uint_as_float(p << 16); }
__device__ __forceinline__ float bfhi(unsigned p) { return __uint_as_float(p & 0xffff0000u); }

// ---------------- pass A1: bucket histogram (block-aggregated atomics) ----------------

__global__ __launch_bounds__(256) void hist_kernel(const int* __restrict__ cols,
                                                   int* __restrict__ ghist, int nE) {
    __shared__ int h[NBUCK];
    const int tid = threadIdx.x;
    for (int i = tid; i < NBUCK; i += 256) h[i] = 0;
    __syncthreads();
    long base = (long)blockIdx.x * EPB;
    for (int j = tid; j < EPB; j += 256) {
        long idx = base + j;
        if (idx < nE) atomicAdd(&h[cols[idx] >> 8], 1);
    }
    __syncthreads();
    for (int i = tid; i < NBUCK; i += 256) {
        int v = h[i];
        if (v) atomicAdd(&ghist[i], v);
    }
}

// ---------------- bucket scan: 391 entries -> gbase, gcursor ----------------

__global__ __launch_bounds__(512) void bucket_scan_kernel(const int* __restrict__ ghist,
                                                          int* __restrict__ gbase,
                                                          int* __restrict__ gcursor) {
    __shared__ int sh[512];
    int t = threadIdx.x;
    int v = (t < NBUCK) ? ghist[t] : 0;
    sh[t] = v;
    __syncthreads();
    for (int off = 1; off < 512; off <<= 1) {
        int add = (t >= off) ? sh[t - off] : 0;
        __syncthreads();
        sh[t] += add;
        __syncthreads();
    }
    if (t < NBUCK) {
        int excl = sh[t] - v;
        gbase[t] = excl;
        gcursor[t] = excl;
    }
}

// ---------------- pass A2: scatter edges into bucket-grouped csc_tmp ----------------
// record: .x = r | ((col&255)<<17), .y = w bits

__global__ __launch_bounds__(256) void scatter_bucket_kernel(const int* __restrict__ rows,
                                                             const int* __restrict__ cols,
                                                             const float* __restrict__ w,
                                                             int* __restrict__ gcursor,
                                                             int2* __restrict__ csc_tmp, int nE) {
    __shared__ int h[NBUCK];
    __shared__ int bb[NBUCK];
    __shared__ unsigned short rk[EPB];
    const int tid = threadIdx.x;
    for (int i = tid; i < NBUCK; i += 256) h[i] = 0;
    __syncthreads();
    long base = (long)blockIdx.x * EPB;
    for (int j = tid; j < EPB; j += 256) {
        long idx = base + j;
        if (idx < nE) rk[j] = (unsigned short)atomicAdd(&h[cols[idx] >> 8], 1);
    }
    __syncthreads();
    for (int i = tid; i < NBUCK; i += 256) {
        int v = h[i];
        if (v) bb[i] = atomicAdd(&gcursor[i], v);
    }
    __syncthreads();
    for (int j = tid; j < EPB; j += 256) {
        long idx = base + j;
        if (idx < nE) {
            int c = cols[idx];
            int b = c >> 8;
            int pos = bb[b] + (int)rk[j];
            csc_tmp[pos] = make_int2((rows[idx] & 0x1FFFF) | ((c & 255) << 17),
                                     __float_as_int(w[idx]));
        }
    }
}

// ---------------- pass B: per-bucket node-level CSC + deg/dinv + starts/cnt ----------------

__global__ __launch_bounds__(256) void build_csc_kernel(const int2* __restrict__ csc_tmp,
                                                        const int* __restrict__ gbase,
                                                        const int* __restrict__ ghist,
                                                        int2* __restrict__ edges,
                                                        int* __restrict__ starts,
                                                        int* __restrict__ cnt,
                                                        float* __restrict__ dinv, int n) {
    __shared__ int ncnt[256];
    __shared__ float nws[256];
    __shared__ int sh[256];
    __shared__ int ncur[256];
    const int tid = threadIdx.x;
    const int b = blockIdx.x;
    const int base = gbase[b];
    const int cntb = ghist[b];

    ncnt[tid] = 0;
    nws[tid] = 0.f;
    __syncthreads();

    // sweep 1: per-node count + weight sum
    for (int i = tid; i < cntb; i += 256) {
        int2 rec = csc_tmp[base + i];
        int local = ((unsigned)rec.x) >> 17;
        atomicAdd(&ncnt[local], 1);
        atomicAdd(&nws[local], __int_as_float(rec.y));
    }
    __syncthreads();

    // exclusive scan over 256 node counts
    int v = ncnt[tid];
    sh[tid] = v;
    __syncthreads();
    for (int off = 1; off < 256; off <<= 1) {
        int add = (tid >= off) ? sh[tid - off] : 0;
        __syncthreads();
        sh[tid] += add;
        __syncthreads();
    }
    int excl = sh[tid] - v;
    ncur[tid] = excl;

    int node = (b << 8) + tid;
    if (node < n) {
        cnt[node] = v;
        starts[node] = base + excl;
        dinv[node] = rsqrtf(1.0f + nws[tid]);
    }
    __syncthreads();

    // sweep 2: place edges at exact node positions
    for (int i = tid; i < cntb; i += 256) {
        int2 rec = csc_tmp[base + i];
        int local = ((unsigned)rec.x) >> 17;
        int r = rec.x & 0x1FFFF;
        int pos = base + atomicAdd(&ncur[local], 1);
        edges[pos] = make_int2(r, rec.y);
    }
}

// ---------------- weight transpose + bf16 pack: W[K][Nn] f32 -> WT[Nn][K/2] dwords ----------------

__global__ void transpose_bf_kernel(const float* __restrict__ W, unsigned* __restrict__ WT,
                                    int K, int Nn) {
    int idx = blockIdx.x * blockDim.x + threadIdx.x;
    int total = Nn * (K / 2);
    if (idx < total) {
        int n = idx / (K / 2);
        int kp = idx - n * (K / 2);
        WT[idx] = packbf2(W[(2 * kp) * Nn + n], W[(2 * kp + 1) * Nn + n]);
    }
}

// ---------------- MFMA bf16 GEMM: C[M,NT] = A[M,KK] @ BT^T, epilogue *rowscale -> bf16 ----------------

template <int NT, int KK, bool ABF16>
__global__ __launch_bounds__(256) void gemm_mfma(const void* __restrict__ Av,
                                                 const unsigned* __restrict__ BT,
                                                 const float* __restrict__ rowscale,
                                                 unsigned short* __restrict__ C,
                                                 int M) {
    constexpr int CT = NT / 16;
    constexpr int KD = KK / 2;          // dwords per bf16 row
    __shared__ unsigned Al[4][128][4];
    __shared__ unsigned Bl[4][NT][4];
    const int tid = threadIdx.x;
    const int wave = tid >> 6;
    const int lane = tid & 63;
    const int quad = lane >> 4;
    const int l16 = lane & 15;
    const int row0 = blockIdx.x * 128;

    f32x4 acc[2][CT] = {};

    for (int k0 = 0; k0 < KK; k0 += 32) {
        // ---- stage A ----
        if (ABF16) {
            const unsigned* Ab = (const unsigned*)Av;
            #pragma unroll
            for (int i = 0; i < 2; i++) {
                int idx = tid + i * 256;
                int ar = idx >> 2, aq = idx & 3;
                uint4 v = make_uint4(0, 0, 0, 0);
                if (row0 + ar < M)
                    v = *(const uint4*)(Ab + (long)(row0 + ar) * KD + k0 / 2 + aq * 4);
                *(uint4*)&Al[aq][ar][0] = v;
            }
        } else {
            const float* Af = (const float*)Av;
            int ar = tid >> 1, ah = tid & 1;
            float4 v0 = make_float4(0, 0, 0, 0), v1 = v0, v2 = v0, v3 = v0;
            if (row0 + ar < M) {
                const float* p = Af + (long)(row0 + ar) * KK + k0 + ah * 16;
                v0 = *(const float4*)p;
                v1 = *(const float4*)(p + 4);
                v2 = *(const float4*)(p + 8);
                v3 = *(const float4*)(p + 12);
            }
            uint4 d0 = make_uint4(packbf2(v0.x, v0.y), packbf2(v0.z, v0.w),
                                  packbf2(v1.x, v1.y), packbf2(v1.z, v1.w));
            uint4 d1 = make_uint4(packbf2(v2.x, v2.y), packbf2(v2.z, v2.w),
                                  packbf2(v3.x, v3.y), packbf2(v3.z, v3.w));
            *(uint4*)&Al[ah * 2 + 0][ar][0] = d0;
            *(uint4*)&Al[ah * 2 + 1][ar][0] = d1;
        }
        // ---- stage B ----
        #pragma unroll
        for (int i = 0; i < NT / 64; i++) {
            int idx = tid + i * 256;
            int br = idx >> 2, bq = idx & 3;
            *(uint4*)&Bl[bq][br][0] = *(const uint4*)(BT + (long)br * KD + k0 / 2 + bq * 4);
        }
        __syncthreads();

        bf16x8 af[2];
        #pragma unroll
        for (int rt = 0; rt < 2; rt++)
            af[rt] = *(const bf16x8*)&Al[quad][wave * 32 + rt * 16 + l16][0];
        #pragma unroll
        for (int ct = 0; ct < CT; ct++) {
            bf16x8 bfr = *(const bf16x8*)&Bl[quad][ct * 16 + l16][0];
            acc[0][ct] = __builtin_amdgcn_mfma_f32_16x16x32_bf16(af[0], bfr, acc[0][ct], 0, 0, 0);
            acc[1][ct] = __builtin_amdgcn_mfma_f32_16x16x32_bf16(af[1], bfr, acc[1][ct], 0, 0, 0);
        }
        __syncthreads();
    }

    // epilogue: C/D layout col=lane&15, row=quad*4+reg
    #pragma unroll
    for (int rt = 0; rt < 2; rt++) {
        #pragma unroll
        for (int reg = 0; reg < 4; reg++) {
            int row = row0 + wave * 32 + rt * 16 + quad * 4 + reg;
            if (row < M) {
                float sc = rowscale[row];
                unsigned short* cp = C + (long)row * NT + l16;
                #pragma unroll
                for (int ct = 0; ct < CT; ct++)
                    cp[ct * 16] = f2bf(acc[rt][ct][reg] * sc);
            }
        }
    }
}

// ---------------- gather-aggregate over bf16 features ----------------
// OUTMODE: 0 = f32 out, 1 = bf16 out, 2 = fused global-add-pool
// Inner loop is software-pipelined: the NEXT batch of 4 edge records is
// loaded while the CURRENT batch's 4 feature gathers are in flight, so the
// serial chain per batch is one gather latency, not edge-latency + gather.

template <int F, bool RELU, int OUTMODE>
__global__ __launch_bounds__(256) void gather_agg_bf(const unsigned* __restrict__ xsb,
                                                     const int2* __restrict__ edges,
                                                     const int* __restrict__ starts,
                                                     const int* __restrict__ cnt,
                                                     const float* __restrict__ dinv,
                                                     const float* __restrict__ bias,
                                                     const int* __restrict__ batch,
                                                     void* __restrict__ outv, int n) {
    constexpr int G = F / 8;        // lanes per node; each lane covers 8 features
    constexpr int FU = F / 2;       // uints per row
    int gt = blockIdx.x * blockDim.x + threadIdx.x;
    int node = gt / G;
    int lane = gt - node * G;

    if (OUTMODE != 2 && node >= n) return;
    bool active = (node < n);

    // LDS pool buckets (only used for OUTMODE==2)
    __shared__ float lp[4][64];
    int g0 = 0;
    if (OUTMODE == 2) {
        lp[threadIdx.x >> 6][threadIdx.x & 63] = 0.f;
        int firstnode = (blockIdx.x * blockDim.x) / G;
        if (firstnode >= n) firstnode = n - 1;
        g0 = batch[firstnode];
        __syncthreads();
    }

    float acc[8] = {};
    float d = 0.f;
    const unsigned* lbase = xsb + lane * 4;
    uint4 sp = make_uint4(0, 0, 0, 0);
    float4 bb0 = make_float4(0, 0, 0, 0), bb1 = bb0;

    if (active) {
        // hoisted independent loads: overlap with first edge-record fetch
        d = dinv[node];
        sp = *(const uint4*)(lbase + (long)node * FU);
        bb0 = ((const float4*)bias)[lane * 2];
        bb1 = ((const float4*)bias)[lane * 2 + 1];

        int s = starts[node];
        int c = cnt[node];
        int e = s + c;
        int j = s;

        // ---- software-pipelined unroll-4 main loop ----
        long long q0 = 0, q1 = 0, q2 = 0, q3 = 0;
        bool have = (j + 4 <= e);
        if (have) {
            const long long* ep = (const long long*)(edges + j);
            q0 = ep[0]; q1 = ep[1]; q2 = ep[2]; q3 = ep[3];
            j += 4;
        }
        while (have) {
            int r0 = (int)q0, r1 = (int)q1, r2 = (int)q2, r3 = (int)q3;
            float w0 = __int_as_float((int)(q0 >> 32));
            float w1 = __int_as_float((int)(q1 >> 32));
            float w2 = __int_as_float((int)(q2 >> 32));
            float w3 = __int_as_float((int)(q3 >> 32));
            uint4 p0 = *(const uint4*)(lbase + (long)r0 * FU);
            uint4 p1 = *(const uint4*)(lbase + (long)r1 * FU);
            uint4 p2 = *(const uint4*)(lbase + (long)r2 * FU);
            uint4 p3 = *(const uint4*)(lbase + (long)r3 * FU);
            // prefetch next batch of edge records while gathers are in flight
            have = (j + 4 <= e);
            if (have) {
                const long long* ep = (const long long*)(edges + j);
                q0 = ep[0]; q1 = ep[1]; q2 = ep[2]; q3 = ep[3];
                j += 4;
            }
            acc[0] += bflo(p0.x) * w0; acc[1] += bfhi(p0.x) * w0;
            acc[2] += bflo(p0.y) * w0; acc[3] += bfhi(p0.y) * w0;
            acc[4] += bflo(p0.z) * w0; acc[5] += bfhi(p0.z) * w0;
            acc[6] += bflo(p0.w) * w0; acc[7] += bfhi(p0.w) * w0;
            acc[0] += bflo(p1.x) * w1; acc[1] += bfhi(p1.x) * w1;
            acc[2] += bflo(p1.y) * w1; acc[3] += bfhi(p1.y) * w1;
            acc[4] += bflo(p1.z) * w1; acc[5] += bfhi(p1.z) * w1;
            acc[6] += bflo(p1.w) * w1; acc[7] += bfhi(p1.w) * w1;
            acc[0] += bflo(p2.x) * w2; acc[1] += bfhi(p2.x) * w2;
            acc[2] += bflo(p2.y) * w2; acc[3] += bfhi(p2.y) * w2;
            acc[4] += bflo(p2.z) * w2; acc[5] += bfhi(p2.z) * w2;
            acc[6] += bflo(p2.w) * w2; acc[7] += bfhi(p2.w) * w2;
            acc[0] += bflo(p3.x) * w3; acc[1] += bfhi(p3.x) * w3;
            acc[2] += bflo(p3.y) * w3; acc[3] += bfhi(p3.y) * w3;
            acc[4] += bflo(p3.z) * w3; acc[5] += bfhi(p3.z) * w3;
            acc[6] += bflo(p3.w) * w3; acc[7] += bfhi(p3.w) * w3;
        }
        // tail
        for (; j < e; j++) {
            int2 ed = edges[j];
            float wv = __int_as_float(ed.y);
            uint4 p = *(const uint4*)(lbase + (long)ed.x * FU);
            acc[0] += bflo(p.x) * wv; acc[1] += bfhi(p.x) * wv;
            acc[2] += bflo(p.y) * wv; acc[3] += bfhi(p.y) * wv;
            acc[4] += bflo(p.z) * wv; acc[5] += bfhi(p.z) * wv;
            acc[6] += bflo(p.w) * wv; acc[7] += bfhi(p.w) * wv;
        }
    }

    float r[8] = {};
    if (active) {
        float sv[8] = { bflo(sp.x), bfhi(sp.x), bflo(sp.y), bfhi(sp.y),
                        bflo(sp.z), bfhi(sp.z), bflo(sp.w), bfhi(sp.w) };
        float bbv[8] = { bb0.x, bb0.y, bb0.z, bb0.w, bb1.x, bb1.y, bb1.z, bb1.w };
        #pragma unroll
        for (int i = 0; i < 8; i++) {
            float v = d * (acc[i] + sv[i]) + bbv[i];
            r[i] = RELU ? fmaxf(v, 0.f) : v;
        }
    }

    if (OUTMODE == 1) {
        if (active) {
            unsigned* ob = (unsigned*)outv;
            uint4 pk = make_uint4(packbf2(r[0], r[1]), packbf2(r[2], r[3]),
                                  packbf2(r[4], r[5]), packbf2(r[6], r[7]));
            *(uint4*)(ob + (long)node * FU + lane * 4) = pk;
        }
    } else if (OUTMODE == 0) {
        if (active) {
            float* o = (float*)outv + (long)node * F + lane * 8;
            *(float4*)o       = make_float4(r[0], r[1], r[2], r[3]);
            *(float4*)(o + 4) = make_float4(r[4], r[5], r[6], r[7]);
        }
    } else {
        // fused global_add_pool: LDS partial sums by (graph - g0), then few atomics
        float* pooled = (float*)outv;
        if (active) {
            int g = batch[node];
            int rel = g - g0;
            if (rel >= 0 && rel < 4) {
                #pragma unroll
                for (int i = 0; i < 8; i++)
                    atomicAdd(&lp[rel][lane * 8 + i], r[i]);
            } else {
                #pragma unroll
                for (int i = 0; i < 8; i++)
                    atomicAdd(&pooled[g * 64 + lane * 8 + i], r[i]);
            }
        }
        __syncthreads();
        int idx = threadIdx.x;           // 256 threads cover 4x64 slots exactly
        int rel = idx >> 6, feat = idx & 63;
        float v = lp[rel][feat];
        int g = g0 + rel;
        if (v != 0.f && g < NUM_GRAPHS)
            atomicAdd(&pooled[g * 64 + feat], v);
    }
}

// ---------------- head: 256 threads, all-LDS MLP + log_softmax + argmax ----------------

__global__ __launch_bounds__(256) void head_kernel(const float* __restrict__ pooled,
                                                   const float* __restrict__ l1w,
                                                   const float* __restrict__ l1b,
                                                   const float* __restrict__ l2w,
                                                   const float* __restrict__ l2b,
                                                   float* __restrict__ out) {
    __shared__ float P[64][68];
    __shared__ float W[64][68];
    __shared__ float red0[64][4];
    __shared__ float red1[64][4];
    const int tid = threadIdx.x;

    for (int i = tid; i < 1024; i += 256) {
        int r = i >> 4;
        int cq = (i & 15) * 4;
        *(float4*)&P[r][cq] = *(const float4*)&pooled[r * 64 + cq];
        *(float4*)&W[r][cq] = *(const float4*)&l1w[r * 64 + cq];
    }
    __syncthreads();

    const int g = tid >> 2;
    const int q = tid & 3;
    const int j0 = q * 16;

    float hacc[16];
    #pragma unroll
    for (int jj = 0; jj < 16; jj++) hacc[jj] = l1b[j0 + jj];

    for (int c = 0; c < 64; c++) {
        float pv = P[g][c];
        #pragma unroll
        for (int jj = 0; jj < 16; jj += 4) {
            float4 wv = *(const float4*)&W[c][j0 + jj];
            hacc[jj + 0] += pv * wv.x;
            hacc[jj + 1] += pv * wv.y;
            hacc[jj + 2] += pv * wv.z;
            hacc[jj + 3] += pv * wv.w;
        }
    }

    float o0 = 0.f, o1 = 0.f;
    #pragma unroll
    for (int jj = 0; jj < 16; jj++) {
        float h = fmaxf(hacc[jj], 0.f);
        o0 += h * l2w[(j0 + jj) * 2];
        o1 += h * l2w[(j0 + jj) * 2 + 1];
    }
    red0[g][q] = o0;
    red1[g][q] = o1;
    __syncthreads();

    if (q == 0) {
        float a0 = red0[g][0] + red0[g][1] + red0[g][2] + red0[g][3] + l2b[0];
        float a1 = red1[g][0] + red1[g][1] + red1[g][2] + red1[g][3] + l2b[1];
        float m = fmaxf(a0, a1);
        float lse = m + logf(expf(a0 - m) + expf(a1 - m));
        out[g * 2 + 0] = a0 - lse;
        out[g * 2 + 1] = a1 - lse;
        out[128 + g] = (a1 > a0) ? 1.f : 0.f;
        out[192 + g * 2 + 0] = a0;
        out[192 + g * 2 + 1] = a1;
    }
}

// ---------------- launch ----------------

extern "C" void kernel_launch(void* const* d_in, const int* in_sizes, int n_in,
                              void* d_out, int out_size, void* d_ws, size_t ws_size,
                              hipStream_t stream) {
    const float* x   = (const float*)d_in[0];           // [N, 256]
    const int* eidx  = (const int*)d_in[1];             // [2, E] flat
    const float* ew  = (const float*)d_in[2];           // [E]
    const int* batch = (const int*)d_in[3];             // [N]
    const float* W1  = (const float*)d_in[4];           // [256,128]
    const float* b1  = (const float*)d_in[5];
    const float* W2  = (const float*)d_in[6];           // [128,64]
    const float* b2  = (const float*)d_in[7];
    const float* l1w = (const float*)d_in[8];           // [64,64]
    const float* l1b = (const float*)d_in[9];
    const float* l2w = (const float*)d_in[10];          // [64,2]
    const float* l2b = (const float*)d_in[11];
    float* out = (float*)d_out;

    const int N = N_NODES, E = N_EDGES;
    const int* rows = eidx;
    const int* cols = eidx + E;

    // workspace layout (float offsets; 16B alignment for vector arrays)
    float* ws = (float*)d_ws;
    int*   ghist   = (int*)ws;                  // 391   -> pad to 512
    int*   gbase   = ghist + 512;               // 391   -> pad to 512
    int*   gcursor = gbase + 512;               // 391   -> pad to 512
    float* dinv    = (float*)(gcursor + 512);   // N
    int*   cnt     = (int*)(dinv + N);          // N
    int*   starts  = cnt + N;                   // N
    unsigned* w1t  = (unsigned*)(starts + N);   // 16384
    unsigned* w2t  = w1t + 16384;               // 4096
    int2*  csc_tmp = (int2*)(w2t + 4096);       // E int2 (16B-aligned)
    int2*  edges   = csc_tmp + E;               // E int2
    unsigned* xsb  = (unsigned*)(edges + E);    // N*64 dw
    unsigned* h1b  = xsb + (long)N * 64;        // N*64 dw
    float* pooled  = (float*)(h1b + (long)N * 64);  // 4096
    unsigned* hw2b = xsb;                       // reuse dead xsb: N*32 dw

    // 1. bucket histogram (block-aggregated atomics)
    hipMemsetAsync(ghist, 0, 512 * sizeof(int), stream);
    hist_kernel<<<NBLK_A, 256, 0, stream>>>(cols, ghist, E);

    // 2. bucket scan
    bucket_scan_kernel<<<1, 512, 0, stream>>>(ghist, gbase, gcursor);

    // 3. scatter into bucket-grouped tmp
    scatter_bucket_kernel<<<NBLK_A, 256, 0, stream>>>(rows, cols, ew, gcursor, csc_tmp, E);

    // 4. per-bucket node-level CSC + deg/dinv/starts/cnt
    build_csc_kernel<<<NBUCK, 256, 0, stream>>>(csc_tmp, gbase, ghist, edges, starts, cnt, dinv, N);

    // 5. weight prep
    transpose_bf_kernel<<<64, 256, 0, stream>>>(W1, w1t, NFEAT, NHID1);
    transpose_bf_kernel<<<16, 256, 0, stream>>>(W2, w2t, NHID1, NCLASS);

    // 6. GEMM1 (MFMA): xsb = bf16((x @ W1) * dinv[row])
    gemm_mfma<NHID1, NFEAT, false><<<(N + 127) / 128, 256, 0, stream>>>(
        x, w1t, dinv, (unsigned short*)xsb, N);

    // 7. gather layer 1: h1b = bf16(relu(dinv[c]*(agg + self) + b1))
    {
        long threads = (long)N * (NHID1 / 8);
        gather_agg_bf<NHID1, true, 1><<<(threads + 255) / 256, 256, 0, stream>>>(
            xsb, edges, starts, cnt, dinv, b1, batch, h1b, N);
    }

    // 8. GEMM2 (MFMA): hw2b = bf16((h1 @ W2) * dinv[row])  (into dead xsb region)
    gemm_mfma<NCLASS, NHID1, true><<<(N + 127) / 128, 256, 0, stream>>>(
        h1b, w2t, dinv, (unsigned short*)hw2b, N);

    // 9. gather layer 2 + fused global_add_pool (no h2 materialization)
    hipMemsetAsync(pooled, 0, NUM_GRAPHS * NCLASS * sizeof(float), stream);
    {
        long threads = (long)N * (NCLASS / 8);
        gather_agg_bf<NCLASS, true, 2><<<(threads + 255) / 256, 256, 0, stream>>>(
            hw2b, edges, starts, cnt, dinv, b2, batch, pooled, N);
    }

    // 10. head
    head_kernel<<<1, 256, 0, stream>>>(pooled, l1w, l1b, l2w, l2b, out);
}